// Round 1
// baseline (894.250 us; speedup 1.0000x reference)
//
#include <hip/hip_runtime.h>

#define CLIP 127

// ---------------- Pass 0: init the atomicMax slot ----------------
__global__ void init_ws_kernel(int* __restrict__ ws) {
    ws[0] = 0;
}

// ---------------- Pass 1: global max|grad| reduction ----------------
__global__ __launch_bounds__(256) void maxabs_kernel(const int* __restrict__ g,
                                                     int n4, int* __restrict__ ws) {
    const int4* g4 = (const int4*)g;
    int tid = blockIdx.x * blockDim.x + threadIdx.x;
    int stride = gridDim.x * blockDim.x;
    int m = 0;
    for (int i = tid; i < n4; i += stride) {
        int4 v = g4[i];
        m = max(m, abs(v.x));
        m = max(m, abs(v.y));
        m = max(m, abs(v.z));
        m = max(m, abs(v.w));
    }
    // wave-64 shuffle reduction
    #pragma unroll
    for (int off = 32; off > 0; off >>= 1)
        m = max(m, __shfl_down(m, off, 64));
    __shared__ int sm[4];
    int lane = threadIdx.x & 63;
    int wave = threadIdx.x >> 6;
    if (lane == 0) sm[wave] = m;
    __syncthreads();
    if (threadIdx.x == 0) {
        int r = max(max(sm[0], sm[1]), max(sm[2], sm[3]));
        atomicMax(ws, r);   // device-scope by default — cross-XCD safe
    }
}

// ---------------- Pass 2: elementwise psto-shift + weight update ----------------
__device__ __forceinline__ int psto_one(int x, int ss, int hs, int mask, int hmask, int oddmul) {
    int rt   = x >> ss;            // floor division (arithmetic shift)
    int prob = x & mask;           // remainder in [0, 2^ss) — abs is a no-op
    int qprob = prob >> hs;
    int prn  = (prob & hmask) * oddmul;
    int sgn  = (x > 0) - (x < 0);
    int dec  = (qprob <= prn) ? 0 : sgn;
    int r    = rt + dec;
    return min(max(r, -CLIP), CLIP);
}

__global__ __launch_bounds__(256) void update_kernel(const int* __restrict__ weight,
                                                     const int* __restrict__ grad,
                                                     const int* __restrict__ err_exp_p,
                                                     const int* __restrict__ act_in_exp_p,
                                                     const int* __restrict__ mu_p,
                                                     const int* __restrict__ ws,
                                                     int* __restrict__ out, int n) {
    int n4  = n >> 2;
    int tid = blockIdx.x * blockDim.x + threadIdx.x;
    if (tid >= n4) return;

    // scalar (wave-uniform) config — exact integer ceil(log2())
    int rng = ws[0];
    int mu  = mu_p[0];
    int bw  = (rng <= 1) ? 0 : (32 - __clz(rng - 1));  // ceil(log2(rng)) for rng>=1
    int shift = bw - mu;
    int ss    = max(shift, 1);
    int hs    = ss >> 1;
    int oddmul = 1 + (ss & 1);
    int mask   = (1 << ss) - 1;
    int hmask  = (1 << hs) - 1;
    bool zero_all = (bw == 0);
    bool trunc_path = (shift < 1);

    const int4* g4 = (const int4*)grad;
    const int4* w4 = (const int4*)weight;
    int4 gv = g4[tid];
    int4 wv = w4[tid];

    int gx, gy, gz, gw;
    if (zero_all) {
        gx = gy = gz = gw = 0;
    } else if (trunc_path) {
        gx = (int)(signed char)gv.x;  // int8 wraparound, matches .astype(int8)
        gy = (int)(signed char)gv.y;
        gz = (int)(signed char)gv.z;
        gw = (int)(signed char)gv.w;
    } else {
        gx = psto_one(gv.x, ss, hs, mask, hmask, oddmul);
        gy = psto_one(gv.y, ss, hs, mask, hmask, oddmul);
        gz = psto_one(gv.z, ss, hs, mask, hmask, oddmul);
        gw = psto_one(gv.w, ss, hs, mask, hmask, oddmul);
    }

    int4 wo;
    wo.x = min(max(wv.x - gx, -CLIP), CLIP);
    wo.y = min(max(wv.y - gy, -CLIP), CLIP);
    wo.z = min(max(wv.z - gz, -CLIP), CLIP);
    wo.w = min(max(wv.w - gw, -CLIP), CLIP);

    int4 go = make_int4(gx, gy, gz, gw);

    int4* outw4 = (int4*)out;
    int4* outg4 = (int4*)(out + n);
    outw4[tid] = wo;
    outg4[tid] = go;

    if (tid == 0) {
        int gs = (zero_all || trunc_path) ? 0 : shift;
        out[2 * n] = err_exp_p[0] + gs + act_in_exp_p[0];
    }
}

extern "C" void kernel_launch(void* const* d_in, const int* in_sizes, int n_in,
                              void* d_out, int out_size, void* d_ws, size_t ws_size,
                              hipStream_t stream) {
    const int* weight     = (const int*)d_in[0];
    const int* grad       = (const int*)d_in[1];
    const int* err_exp    = (const int*)d_in[2];
    const int* act_in_exp = (const int*)d_in[3];
    const int* mu         = (const int*)d_in[4];
    int* out = (int*)d_out;
    int* ws  = (int*)d_ws;

    int n  = in_sizes[1];       // 8192*8192 grad elements
    int n4 = n >> 2;

    hipMemsetAsync(ws, 0, sizeof(int), stream);  // capture-safe memset node
    maxabs_kernel<<<4096, 256, 0, stream>>>(grad, n4, ws);
    int blocks = (n4 + 255) / 256;
    update_kernel<<<blocks, 256, 0, stream>>>(weight, grad, err_exp, act_in_exp, mu, ws, out, n);
}